// Round 16
// baseline (217.348 us; speedup 1.0000x reference)
//
#include <hip/hip_runtime.h>
#include <hip/hip_bf16.h>

#define BB 2
#define N_TOK 4280
#define NPAD 4352            /* 34 * 128 */
#define MPAD 8576
#define WH 4096
#define NOBJ 30
#define QDIM 320
#define HEADS 8
#define DHEAD 40
#define M_ROWS (BB * N_TOK)  /* 8560 */
#define NT64 (NPAD / 64)     /* 68 */
#define NQT (NPAD / 128)     /* 34 q-tiles of 128 */
#define KSPLIT 4
#define NTH (NT64 / KSPLIT)  /* 17 tiles per quarter */

typedef __attribute__((ext_vector_type(8))) short short8;
typedef __attribute__((ext_vector_type(4))) short short4v;
typedef __attribute__((ext_vector_type(4))) float f32x4;
typedef __attribute__((ext_vector_type(4))) unsigned uintx4;

#define GLD16(lds, g) __builtin_amdgcn_global_load_lds( \
    (const __attribute__((address_space(1))) unsigned*)(g), \
    (__attribute__((address_space(3))) unsigned*)(lds), 16, 0, 0)
#define GLD4(lds, g) __builtin_amdgcn_global_load_lds( \
    (const __attribute__((address_space(1))) unsigned*)(g), \
    (__attribute__((address_space(3))) unsigned*)(lds), 4, 0, 0)

__device__ __forceinline__ ushort f2bf(float x) {
    union { __hip_bfloat16 h; ushort u; } cv;
    cv.h = __float2bfloat16(x);
    return cv.u;
}
__device__ __forceinline__ float bf2f(ushort u) {
    union { unsigned u; float f; } cv;
    cv.u = ((unsigned)u) << 16;
    return cv.f;
}

// ---- fused preproc: x->bf16 (all gids); bits pack (gid<BB*NPAD); MQK zero ---
__global__ void k_pre(const float* __restrict__ x, ushort* __restrict__ xb,
                      const float* __restrict__ att, unsigned* __restrict__ bits,
                      unsigned* __restrict__ MQK) {
    int gid = blockIdx.x * blockDim.x + threadIdx.x;
    if (gid < 32) MQK[gid] = 0;
    if (gid < BB * NPAD) {
        int b = gid / NPAD, i = gid - b * NPAD;
        unsigned v = 0;
        if (i < WH) {
            const float* base = att + (size_t)b * NOBJ * WH + i;
            #pragma unroll
            for (int o = 0; o < NOBJ; ++o)
                if (base[(size_t)o * WH] > 0.5f) v |= (1u << o);
        }
        bits[gid] = v;
    }
    if (gid >= M_ROWS * QDIM / 8) return;
    float4 v0 = ((const float4*)x)[gid * 2];
    float4 v1 = ((const float4*)x)[gid * 2 + 1];
    short8 o;
    o[0] = (short)f2bf(v0.x); o[1] = (short)f2bf(v0.y);
    o[2] = (short)f2bf(v0.z); o[3] = (short)f2bf(v0.w);
    o[4] = (short)f2bf(v1.x); o[5] = (short)f2bf(v1.y);
    o[6] = (short)f2bf(v1.z); o[7] = (short)f2bf(v1.w);
    ((short8*)xb)[gid] = o;
}

// ------ weights -> bf16, transposed: WtAll[1280][320]; rows 0-959 = QKV^T ---
__global__ __launch_bounds__(256) void k_wcvt(const float* __restrict__ Wq,
                                              const float* __restrict__ Wk,
                                              const float* __restrict__ Wv,
                                              const float* __restrict__ Wo,
                                              ushort* __restrict__ WtAll) {
    __shared__ float T[32][33];
    const int k0 = blockIdx.x * 32;
    const int np0 = blockIdx.y * 32;
    const float SC = 0.15811388300841897f * 1.4426950408889634f; // scale*log2e
    const float* src; int n0; float sc = 1.f;
    if (np0 < 320)      { src = Wq; n0 = np0;       sc = SC; }
    else if (np0 < 640) { src = Wk; n0 = np0 - 320; }
    else if (np0 < 960) { src = Wv; n0 = np0 - 640; }
    else                { src = Wo; n0 = np0 - 960; }
    const int tid = threadIdx.x;
    #pragma unroll
    for (int it = 0; it < 4; ++it) {
        int idx = tid + it * 256;
        int r = idx >> 5, c = idx & 31;
        T[r][c] = src[(size_t)(k0 + r) * QDIM + n0 + c];
    }
    __syncthreads();
    #pragma unroll
    for (int it = 0; it < 4; ++it) {
        int idx = tid + it * 256;
        int rr = idx >> 5, cc = idx & 31;
        WtAll[(size_t)(np0 + rr) * QDIM + k0 + cc] = f2bf(T[cc][rr] * sc);
    }
}

// -------------------- MFMA GEMM: C[m][n] = A[m][:] . Wt[n][:] ---------------
template<int IS_OUT>
__global__ __launch_bounds__(256) void k_mm(const ushort* __restrict__ A,
                                            const ushort* __restrict__ Wt,
                                            const float* __restrict__ bias,
                                            ushort* __restrict__ Qb,
                                            ushort* __restrict__ Kb,
                                            ushort* __restrict__ Vt,
                                            float* __restrict__ Cout) {
    __shared__ __align__(16) char Ab[2][8192];
    __shared__ __align__(16) char Bb[2][8192];
    const int tid = threadIdx.x, lane = tid & 63, wv = tid >> 6;
    const int g = lane >> 4, c16 = lane & 15, l7 = lane & 7;
    const int rsub = lane >> 3, slotx = lane & 7;
    const int m0 = blockIdx.x * 64;
    const int nt = blockIdx.y;

    f32x4 acc[4] = {{0,0,0,0},{0,0,0,0},{0,0,0,0},{0,0,0,0}};

    auto STAGE = [&](int ks, int bufi) {
        const int k0 = ks * 64;
        #pragma unroll
        for (int u = 0; u < 2; ++u) {
            int r0 = wv * 16 + u * 8;
            int row = r0 + rsub;
            int slot = slotx ^ (row & 7);
            GLD16(Ab[bufi] + r0 * 128, A + (size_t)(m0 + row) * QDIM + k0 + slot * 8);
            GLD16(Bb[bufi] + r0 * 128, Wt + (size_t)(nt * 64 + row) * QDIM + k0 + slot * 8);
        }
    };

    const int sl0 = (g ^ l7) * 16, sl1 = ((4 + g) ^ l7) * 16;

    STAGE(0, 0);
    __syncthreads();
    int cur = 0;
    for (int ks = 0; ks < 5; ++ks) {
        if (ks < 4) STAGE(ks + 1, cur ^ 1);
        const char* bbase = Bb[cur] + (wv * 16 + c16) * 128;
        short8 bf0 = *(const short8*)(bbase + sl0);
        short8 bf1 = *(const short8*)(bbase + sl1);
        #pragma unroll
        for (int mi = 0; mi < 4; ++mi) {
            const char* abase = Ab[cur] + (mi * 16 + c16) * 128;
            acc[mi] = __builtin_amdgcn_mfma_f32_16x16x32_bf16(*(const short8*)(abase + sl0), bf0, acc[mi], 0, 0, 0);
            acc[mi] = __builtin_amdgcn_mfma_f32_16x16x32_bf16(*(const short8*)(abase + sl1), bf1, acc[mi], 0, 0, 0);
        }
        __syncthreads();
        cur ^= 1;
    }

    const int ng = nt * 64 + wv * 16 + c16;
    if (IS_OUT) {
        float bv = bias[ng];
        #pragma unroll
        for (int mi = 0; mi < 4; ++mi)
            #pragma unroll
            for (int r = 0; r < 4; ++r) {
                int m = m0 + mi * 16 + g * 4 + r;
                if (m < M_ROWS) Cout[(size_t)m * QDIM + ng] = acc[mi][r] + bv;
            }
    } else {
        int p = ng / QDIM, nn = ng - p * QDIM;
        int h = nn / DHEAD, d = nn - h * DHEAD;
        if (p == 2) {
            #pragma unroll
            for (int mi = 0; mi < 4; ++mi) {
                int m = m0 + mi * 16 + g * 4;        // 4-aligned; N_TOK%4==0
                if (m >= M_ROWS) continue;
                int b = m / N_TOK, tok = m - b * N_TOK;
                short4v w4;
                w4[0] = (short)f2bf(acc[mi][0]);
                w4[1] = (short)f2bf(acc[mi][1]);
                w4[2] = (short)f2bf(acc[mi][2]);
                w4[3] = (short)f2bf(acc[mi][3]);
                *(short4v*)(Vt + ((size_t)(b * HEADS + h) * 48 + d) * NPAD + tok) = w4;
            }
        } else {
            ushort* base = (p == 0) ? Qb : Kb;
            #pragma unroll
            for (int mi = 0; mi < 4; ++mi)
                #pragma unroll
                for (int r = 0; r < 4; ++r) {
                    int m = m0 + mi * 16 + g * 4 + r;
                    if (m >= M_ROWS) continue;
                    int b = m / N_TOK, tok = m - b * N_TOK;
                    base[((size_t)(b * HEADS + h) * NPAD + tok) * 64 + d] = f2bf(acc[mi][r]);
                }
        }
    }
}

// ---- per-(b,h) max norms via atomics: MQK[bh]=max||q~||^2, MQK[16+bh]=max||k||^2
__global__ __launch_bounds__(256) void k_norm(const ushort* __restrict__ Qb,
                                              const ushort* __restrict__ Kb,
                                              unsigned* __restrict__ MQK) {
    __shared__ float rq[256], rk[256];
    const int bh = blockIdx.x >> 3, part = blockIdx.x & 7;
    const int tid = threadIdx.x;
    float mq = 0.f, mk = 0.f;
    for (int tok = part * 256 + tid; tok < N_TOK; tok += 2048) {
        const ushort* qp = Qb + ((size_t)bh * NPAD + tok) * 64;
        const ushort* kp = Kb + ((size_t)bh * NPAD + tok) * 64;
        float sq = 0.f, sk = 0.f;
        #pragma unroll
        for (int d8 = 0; d8 < 40; d8 += 8) {
            short8 a = *(const short8*)(qp + d8);
            short8 c = *(const short8*)(kp + d8);
            #pragma unroll
            for (int j = 0; j < 8; ++j) {
                float fa = bf2f((ushort)a[j]), fc = bf2f((ushort)c[j]);
                sq += fa * fa; sk += fc * fc;
            }
        }
        mq = fmaxf(mq, sq); mk = fmaxf(mk, sk);
    }
    rq[tid] = mq; rk[tid] = mk;
    __syncthreads();
    for (int s = 128; s > 0; s >>= 1) {
        if (tid < s) {
            rq[tid] = fmaxf(rq[tid], rq[tid + s]);
            rk[tid] = fmaxf(rk[tid], rk[tid + s]);
        }
        __syncthreads();
    }
    if (tid == 0) {
        atomicMax(&MQK[bh],      __float_as_uint(rq[0]));
        atomicMax(&MQK[16 + bh], __float_as_uint(rk[0]));
    }
}

// ---- patch pad dims: q[40]=-B_h; Kb d40=1(valid)/0, d41..63=0; Vt row40 = 1 -
__global__ void k_patch(ushort* __restrict__ Qb, ushort* __restrict__ Kb,
                        ushort* __restrict__ Vt, const unsigned* __restrict__ MQK) {
    int gid = blockIdx.x * blockDim.x + threadIdx.x;
    if (gid >= 16 * NPAD) return;
    int bh = gid / NPAD, tok = gid - bh * NPAD;
    float B = sqrtf(__uint_as_float(MQK[bh])) * sqrtf(__uint_as_float(MQK[16 + bh]));
    Qb[(size_t)gid * 64 + 40] = f2bf(-B);
    short8 z = {0, 0, 0, 0, 0, 0, 0, 0};
    short8 k1 = z;
    k1[0] = (short)((tok < N_TOK) ? 0x3F80 : 0);      // k[40]
    ushort* krow = Kb + (size_t)gid * 64;
    *(short8*)(krow + 40) = k1;                        // d 40..47
    *(short8*)(krow + 48) = z;                         // d 48..55
    *(short8*)(krow + 56) = z;                         // d 56..63
    Vt[((size_t)bh * 48 + 40) * NPAD + tok] = (tok < N_TOK) ? (ushort)0x3F80 : (ushort)0;
}

// ------------------------------ mask predicate ------------------------------
__device__ __forceinline__ bool mask_ok(int i, int j, unsigned bi, unsigned bj) {
    if (j >= N_TOK) return false;
    if (i == j) return true;
    if (i < WH) {
        if (j < WH) return (bi & bj) != 0u;
        if (j >= WH + 4 * NOBJ) return true;
        int cI = j - WH;
        if ((unsigned)(cI - NOBJ) < (unsigned)(2 * NOBJ)) return true;
        int om = (cI < NOBJ) ? cI : cI - 3 * NOBJ;
        return ((bi >> om) & 1u) != 0u;
    }
    if (j >= WH) return true;
    if (i >= WH + 4 * NOBJ) return true;
    int rI = i - WH;
    if ((unsigned)(rI - NOBJ) < (unsigned)(2 * NOBJ)) return true;
    int om = (rI < NOBJ) ? rI : rI - 3 * NOBJ;
    return ((bj >> om) & 1u) != 0u;
}

// ------ fused attention: split-K x4; 4 waves x 32q; 64-key tiles;
// ------ SINGLE barrier/tile: K+bits double-buffered (full-tile leash),
// ------ V in registers (issued at tile start, hidden by S-phase);
// ------ l via PV MFMA (ones-row); bf16 partials -----------------------------
__global__ __launch_bounds__(256, 4) void k_attn(const ushort* __restrict__ Qb,
                                                 const ushort* __restrict__ Kb,
                                                 const ushort* __restrict__ Vt,
                                                 const unsigned* __restrict__ bits,
                                                 ushort* __restrict__ Opart,
                                                 float* __restrict__ Lpart) {
    __shared__ __align__(16) char KtB[2][8192];      // 16 KB [key][64 d]
    __shared__ __align__(16) char PsB[4 * 4096];     // 16 KB per-wave P
    __shared__ __align__(16) unsigned bJB[2][64];    // 0.5 KB

    const int tid = threadIdx.x;
    const int lane = tid & 63, wv = tid >> 6;
    const int g = lane >> 4, c16 = lane & 15;
    const int l7x = c16 & 7;
    const int rsub = lane >> 3, slotx = lane & 7;

    // XCD-chunked bijective swizzle: 2176 = 8 * 272.
    const int bid = blockIdx.x;
    const int logical = (bid & 7) * 272 + (bid >> 3);
    const int grp = logical / NQT;                 // 0..63 = (bh, ks)
    const int qt = logical - grp * NQT;
    const int bh = grp >> 2, ks = grp & 3;
    const int b = bh >> 3;
    const int q0w = qt * 128 + wv * 32;
    const int iqA = q0w + c16, iqB = iqA + 16;
    const bool vis_i = (qt < 32);
    const int t0 = ks * NTH;                       // first global 64-key tile

    short8 qA0, qA1, qB0, qB1;
    {
        const ushort* qp = Qb + ((size_t)bh * NPAD + iqA) * 64 + g * 8;
        qA0 = *(const short8*)(qp);
        qA1 = *(const short8*)(qp + 32);
        qB0 = *(const short8*)(qp + 16 * 64);
        qB1 = *(const short8*)(qp + 16 * 64 + 32);
    }
    const unsigned bI_A = bits[(size_t)b * NPAD + iqA];
    const unsigned bI_B = bits[(size_t)b * NPAD + iqB];

    // staging pointers (strength-reduced), starting at this quarter's key base
    const ushort* kp = Kb + ((size_t)bh * NPAD + t0 * 64 + wv * 16 + rsub) * 64 + (slotx ^ rsub) * 8;
    const unsigned* bp = bits + (size_t)b * NPAD + t0 * 64 + lane;
    // per-lane V register-load pointers (B-frag layout: row d = j*16+c16, k-slice g*8)
    const ushort* v0p = Vt + ((size_t)bh * 48 +  0 + c16) * NPAD + t0 * 64 + g * 8;
    const ushort* v1p = v0p + (size_t)16 * NPAD;
    const ushort* v2p = v1p + (size_t)16 * NPAD;

    auto STAGE_K = [&](const ushort* kpt, int bi) {
        GLD16(KtB[bi] + (wv * 16) * 128, kpt);
        GLD16(KtB[bi] + (wv * 16 + 8) * 128, kpt + 512);
    };
    auto STAGE_B = [&](const unsigned* bpt, int bi) {
        if (wv == 3) GLD4(bJB[bi], bpt);
    };

    const int sl0 = (g ^ l7x) * 16;
    const int sl1 = ((4 + g) ^ l7x) * 16;
    const int pswA = wv * 4096 + c16 * 128;          // sub A row
    const int pswB = pswA + 2048;                    // sub B row
    const int swz = l7x << 4;

    f32x4 oA0 = {0,0,0,0}, oA1 = oA0, oA2 = oA0;
    f32x4 oB0 = oA0, oB1 = oA0, oB2 = oA0;

    STAGE_K(kp, 0); STAGE_B(bp, 0);
    __syncthreads();
    int cur = 0;

    for (int t = 0; t < NTH; ++t) {
        const int tg = t0 + t;
        const int j0 = tg * 64;

        // ---- issue V register loads for THIS tile (oldest: waits won't drain K)
        short8 v00 = *(const short8*)(v0p), v01 = *(const short8*)(v0p + 32);
        short8 v10 = *(const short8*)(v1p), v11 = *(const short8*)(v1p + 32);
        short8 v20 = *(const short8*)(v2p), v21 = *(const short8*)(v2p + 32);

        // ---- prefetch next K tile + bits into the other buffer (full leash)
        kp += 64 * 64; bp += 64;
        if (t + 1 < NTH) { STAGE_K(kp, cur ^ 1); STAGE_B(bp, cur ^ 1); }

        // ---- S + softmax + P-write, fused per kt (both q-subs) ----
        auto do_tile = [&](auto okA_fn, auto okB_fn) {
            #pragma unroll
            for (int kt = 0; kt < 4; ++kt) {
                const char* arow = KtB[cur] + (kt * 16 + c16) * 128;
                short8 a0 = *(const short8*)(arow + sl0);
                short8 a1 = *(const short8*)(arow + sl1);
                f32x4 sA = {0,0,0,0}, sB = {0,0,0,0};
                __builtin_amdgcn_s_setprio(1);
                sA = __builtin_amdgcn_mfma_f32_16x16x32_bf16(a0, qA0, sA, 0, 0, 0);
                sA = __builtin_amdgcn_mfma_f32_16x16x32_bf16(a1, qA1, sA, 0, 0, 0);
                sB = __builtin_amdgcn_mfma_f32_16x16x32_bf16(a0, qB0, sB, 0, 0, 0);
                sB = __builtin_amdgcn_mfma_f32_16x16x32_bf16(a1, qB1, sB, 0, 0, 0);
                __builtin_amdgcn_s_setprio(0);
                uintx4 bk = *(const uintx4*)&bJB[cur][kt * 16 + g * 4];
                float pA[4], pB[4];
                #pragma unroll
                for (int r = 0; r < 4; ++r) {
                    int j = j0 + kt * 16 + g * 4 + r;
                    float eA = __builtin_amdgcn_exp2f(sA[r]);
                    float eB = __builtin_amdgcn_exp2f(sB[r]);
                    pA[r] = okA_fn(j, bk[r]) ? eA : 0.f;
                    pB[r] = okB_fn(j, bk[r]) ? eB : 0.f;
                }
                unsigned wA0, wA1, wB0, wB1;
                asm("v_cvt_pk_bf16_f32 %0, %1, %2" : "=v"(wA0) : "v"(pA[0]), "v"(pA[1]));
                asm("v_cvt_pk_bf16_f32 %0, %1, %2" : "=v"(wA1) : "v"(pA[2]), "v"(pA[3]));
                asm("v_cvt_pk_bf16_f32 %0, %1, %2" : "=v"(wB0) : "v"(pB[0]), "v"(pB[1]));
                asm("v_cvt_pk_bf16_f32 %0, %1, %2" : "=v"(wB1) : "v"(pB[2]), "v"(pB[3]));
                uint2 vA; vA.x = wA0; vA.y = wA1;
                uint2 vB; vB.x = wB0; vB.y = wB1;
                int po = (kt * 32 + g * 8) ^ swz;
                *(uint2*)(PsB + pswA + po) = vA;
                *(uint2*)(PsB + pswB + po) = vB;
            }
        };

        const bool vis_j = (j0 + 64 <= WH);
        if (vis_i && vis_j && ((tg >> 1) != qt)) {
            do_tile([&](int j, unsigned bj) { return (bI_A & bj) != 0u; },
                    [&](int j, unsigned bj) { return (bI_B & bj) != 0u; });
        } else if (vis_i && vis_j) {
            do_tile([&](int j, unsigned bj) { return ((bI_A & bj) != 0u) || (iqA == j); },
                    [&](int j, unsigned bj) { return ((bI_B & bj) != 0u) || (iqB == j); });
        } else {
            do_tile([&](int j, unsigned bj) { return mask_ok(iqA, j, bI_A, bj); },
                    [&](int j, unsigned bj) { return mask_ok(iqB, j, bI_B, bj); });
        }

        // ---- PV: 12 MFMA from V regs (landed during S-phase);
        // ---- d=40 col of oA2/oB2 accumulates l (ones-row) ----
        short8 paA0 = *(const short8*)(PsB + pswA + sl0);
        short8 paA1 = *(const short8*)(PsB + pswA + sl1);
        short8 paB0 = *(const short8*)(PsB + pswB + sl0);
        short8 paB1 = *(const short8*)(PsB + pswB + sl1);
        {
            __builtin_amdgcn_s_setprio(1);
            oA0 = __builtin_amdgcn_mfma_f32_16x16x32_bf16(paA0, v00, oA0, 0, 0, 0);
            oA0 = __builtin_amdgcn_mfma_f32_16x16x32_bf16(paA1, v01, oA0, 0, 0, 0);
            oB0 = __builtin_amdgcn_mfma_f32_16x16x32_bf16(paB0, v00, oB0, 0, 0, 0);
            oB0 = __builtin_amdgcn_mfma_f32_16x16x32_bf16(paB1, v01, oB0, 0, 0, 0);
            oA1 = __builtin_amdgcn_mfma_f32_16x16x32_bf16(paA0, v10, oA1, 0, 0, 0);
            oA1 = __builtin_amdgcn_mfma_f32_16x16x32_bf16(paA1, v11, oA1, 0, 0, 0);
            oB1 = __builtin_amdgcn_mfma_f32_16x16x32_bf16(paB0, v10, oB1, 0, 0, 0);
            oB1 = __builtin_amdgcn_mfma_f32_16x16x32_bf16(paB1, v11, oB1, 0, 0, 0);
            oA2 = __builtin_amdgcn_mfma_f32_16x16x32_bf16(paA0, v20, oA2, 0, 0, 0);
            oA2 = __builtin_amdgcn_mfma_f32_16x16x32_bf16(paA1, v21, oA2, 0, 0, 0);
            oB2 = __builtin_amdgcn_mfma_f32_16x16x32_bf16(paB0, v20, oB2, 0, 0, 0);
            oB2 = __builtin_amdgcn_mfma_f32_16x16x32_bf16(paB1, v21, oB2, 0, 0, 0);
            __builtin_amdgcn_s_setprio(0);
        }

        v0p += 64; v1p += 64; v2p += 64;
        __syncthreads();   // single barrier: KtB[cur] free for reuse; K(t+1) landed
        cur ^= 1;
    }

    // ---- store partials: O (bf16) + l (f32, d=40 column, lane c16==8) ----
    const size_t prow = ((size_t)ks * 16 + bh) * NPAD;
    if (c16 == 8) {
        #pragma unroll
        for (int r = 0; r < 4; ++r) {
            Lpart[prow + q0w + g * 4 + r]      = oA2[r];
            Lpart[prow + q0w + 16 + g * 4 + r] = oB2[r];
        }
    }
    #pragma unroll
    for (int r = 0; r < 4; ++r) {
        int qrA = q0w + g * 4 + r;
        int qrB = qrA + 16;
        if (qrA < N_TOK) {
            ushort* dst = Opart + (prow + qrA) * 40;
            dst[c16]      = f2bf(oA0[r]);
            dst[16 + c16] = f2bf(oA1[r]);
            if (c16 < 8) dst[32 + c16] = f2bf(oA2[r]);
        }
        if (qrB < N_TOK) {
            ushort* dst = Opart + (prow + qrB) * 40;
            dst[c16]      = f2bf(oB0[r]);
            dst[16 + c16] = f2bf(oB1[r]);
            if (c16 < 8) dst[32 + c16] = f2bf(oB2[r]);
        }
    }
}

// ---------- combine: O = sum(Ok)/sum(lk), write bf16 AOb --------------------
__global__ __launch_bounds__(256) void k_comb(const ushort* __restrict__ Opart,
                                              const float* __restrict__ Lpart,
                                              ushort* __restrict__ AOb) {
    int gid = blockIdx.x * blockDim.x + threadIdx.x;
    if (gid >= 16 * N_TOK * 10) return;
    int row = gid / 10, v = gid - row * 10;
    int bh = row / N_TOK, q = row - bh * N_TOK;
    f32x4 s = {0.f, 0.f, 0.f, 0.f};
    float l = 0.f;
    #pragma unroll
    for (int ks = 0; ks < KSPLIT; ++ks) {
        size_t rr = ((size_t)ks * 16 + bh) * NPAD + q;
        short4v a = *(const short4v*)(Opart + rr * 40 + v * 4);
        s[0] += bf2f((ushort)a[0]); s[1] += bf2f((ushort)a[1]);
        s[2] += bf2f((ushort)a[2]); s[3] += bf2f((ushort)a[3]);
        l += Lpart[rr];
    }
    float inv = 1.f / l;
    int b = bh >> 3, h = bh & 7;
    short4v o;
    o[0] = (short)f2bf(s[0] * inv);
    o[1] = (short)f2bf(s[1] * inv);
    o[2] = (short)f2bf(s[2] * inv);
    o[3] = (short)f2bf(s[3] * inv);
    *(short4v*)(AOb + (size_t)(b * N_TOK + q) * QDIM + h * DHEAD + v * 4) = o;
}

// --------------------------------- launcher ---------------------------------
extern "C" void kernel_launch(void* const* d_in, const int* in_sizes, int n_in,
                              void* d_out, int out_size, void* d_ws, size_t ws_size,
                              hipStream_t stream) {
    const float* x   = (const float*)d_in[0];
    const float* att = (const float*)d_in[1];
    const float* Wq  = (const float*)d_in[2];
    const float* Wk  = (const float*)d_in[3];
    const float* Wv  = (const float*)d_in[4];
    const float* Wo  = (const float*)d_in[5];
    const float* bo  = (const float*)d_in[6];
    float* out = (float*)d_out;

    char* w = (char*)d_ws;
    unsigned* bits = (unsigned*)w;                      // BB*NPAD*4 = 34.8 KB
    unsigned* MQK = (unsigned*)(w + 40960);             // 32 uints
    size_t off = 65536;
    ushort* xb    = (ushort*)(w + off); off += (size_t)MPAD * QDIM * 2;
    ushort* WtAll = (ushort*)(w + off); off += (size_t)1280 * QDIM * 2;
    ushort* Qb    = (ushort*)(w + off); off += (size_t)16 * NPAD * 64 * 2;
    ushort* Kb    = (ushort*)(w + off); off += (size_t)16 * NPAD * 64 * 2;
    ushort* Vt    = (ushort*)(w + off); off += (size_t)16 * 48 * NPAD * 2;
    ushort* AOb   = (ushort*)(w + off); off += (size_t)MPAD * QDIM * 2;
    ushort* Opart = (ushort*)(w + off); off += (size_t)KSPLIT * 16 * NPAD * 40 * 2;
    float*  Lpart = (float*)(w + off);

    k_pre<<<(M_ROWS * QDIM / 8 + 255) / 256, 256, 0, stream>>>(x, xb, att, bits, MQK);
    k_wcvt<<<dim3(10, 40), 256, 0, stream>>>(Wq, Wk, Wv, Wo, WtAll);

    k_mm<0><<<dim3(MPAD / 64, 15), 256, 0, stream>>>(xb, WtAll, nullptr, Qb, Kb, Vt, nullptr);
    k_norm<<<128, 256, 0, stream>>>(Qb, Kb, MQK);
    k_patch<<<(16 * NPAD + 255) / 256, 256, 0, stream>>>(Qb, Kb, Vt, MQK);
    k_attn<<<16 * NQT * KSPLIT, 256, 0, stream>>>(Qb, Kb, Vt, bits, Opart, Lpart);
    k_comb<<<(16 * N_TOK * 10 + 255) / 256, 256, 0, stream>>>(Opart, Lpart, AOb);
    k_mm<1><<<dim3(MPAD / 64, 5), 256, 0, stream>>>(AOb, WtAll + 960 * QDIM, bo,
                                                    nullptr, nullptr, nullptr, out);
}

// Round 17
// 179.795 us; speedup vs baseline: 1.2089x; 1.2089x over previous
//
#include <hip/hip_runtime.h>
#include <hip/hip_bf16.h>

#define BB 2
#define N_TOK 4280
#define NPAD 4352            /* 34 * 128 */
#define MPAD 8576
#define WH 4096
#define NOBJ 30
#define QDIM 320
#define HEADS 8
#define DHEAD 40
#define M_ROWS (BB * N_TOK)  /* 8560 */
#define NT64 (NPAD / 64)     /* 68 */
#define NQT (NPAD / 128)     /* 34 q-tiles of 128 */
#define KSPLIT 4
#define NTH (NT64 / KSPLIT)  /* 17 tiles per quarter */

typedef __attribute__((ext_vector_type(8))) short short8;
typedef __attribute__((ext_vector_type(4))) short short4v;
typedef __attribute__((ext_vector_type(4))) float f32x4;
typedef __attribute__((ext_vector_type(4))) unsigned uintx4;

#define GLD16(lds, g) __builtin_amdgcn_global_load_lds( \
    (const __attribute__((address_space(1))) unsigned*)(g), \
    (__attribute__((address_space(3))) unsigned*)(lds), 16, 0, 0)
#define GLD4(lds, g) __builtin_amdgcn_global_load_lds( \
    (const __attribute__((address_space(1))) unsigned*)(g), \
    (__attribute__((address_space(3))) unsigned*)(lds), 4, 0, 0)

__device__ __forceinline__ ushort f2bf(float x) {
    union { __hip_bfloat16 h; ushort u; } cv;
    cv.h = __float2bfloat16(x);
    return cv.u;
}
__device__ __forceinline__ float bf2f(ushort u) {
    union { unsigned u; float f; } cv;
    cv.u = ((unsigned)u) << 16;
    return cv.f;
}

// ---- fused preproc: x->bf16 (all gids); bits pack (gid<BB*NPAD); MQK zero ---
__global__ void k_pre(const float* __restrict__ x, ushort* __restrict__ xb,
                      const float* __restrict__ att, unsigned* __restrict__ bits,
                      unsigned* __restrict__ MQK) {
    int gid = blockIdx.x * blockDim.x + threadIdx.x;
    if (gid < 32) MQK[gid] = 0;
    if (gid < BB * NPAD) {
        int b = gid / NPAD, i = gid - b * NPAD;
        unsigned v = 0;
        if (i < WH) {
            const float* base = att + (size_t)b * NOBJ * WH + i;
            #pragma unroll
            for (int o = 0; o < NOBJ; ++o)
                if (base[(size_t)o * WH] > 0.5f) v |= (1u << o);
        }
        bits[gid] = v;
    }
    if (gid >= M_ROWS * QDIM / 8) return;
    float4 v0 = ((const float4*)x)[gid * 2];
    float4 v1 = ((const float4*)x)[gid * 2 + 1];
    short8 o;
    o[0] = (short)f2bf(v0.x); o[1] = (short)f2bf(v0.y);
    o[2] = (short)f2bf(v0.z); o[3] = (short)f2bf(v0.w);
    o[4] = (short)f2bf(v1.x); o[5] = (short)f2bf(v1.y);
    o[6] = (short)f2bf(v1.z); o[7] = (short)f2bf(v1.w);
    ((short8*)xb)[gid] = o;
}

// ------ weights -> bf16, transposed: WtAll[1280][320]; rows 0-959 = QKV^T ---
__global__ __launch_bounds__(256) void k_wcvt(const float* __restrict__ Wq,
                                              const float* __restrict__ Wk,
                                              const float* __restrict__ Wv,
                                              const float* __restrict__ Wo,
                                              ushort* __restrict__ WtAll) {
    __shared__ float T[32][33];
    const int k0 = blockIdx.x * 32;
    const int np0 = blockIdx.y * 32;
    const float SC = 0.15811388300841897f * 1.4426950408889634f; // scale*log2e
    const float* src; int n0; float sc = 1.f;
    if (np0 < 320)      { src = Wq; n0 = np0;       sc = SC; }
    else if (np0 < 640) { src = Wk; n0 = np0 - 320; }
    else if (np0 < 960) { src = Wv; n0 = np0 - 640; }
    else                { src = Wo; n0 = np0 - 960; }
    const int tid = threadIdx.x;
    #pragma unroll
    for (int it = 0; it < 4; ++it) {
        int idx = tid + it * 256;
        int r = idx >> 5, c = idx & 31;
        T[r][c] = src[(size_t)(k0 + r) * QDIM + n0 + c];
    }
    __syncthreads();
    #pragma unroll
    for (int it = 0; it < 4; ++it) {
        int idx = tid + it * 256;
        int rr = idx >> 5, cc = idx & 31;
        WtAll[(size_t)(np0 + rr) * QDIM + k0 + cc] = f2bf(T[cc][rr] * sc);
    }
}

// -------------------- MFMA GEMM: C[m][n] = A[m][:] . Wt[n][:] ---------------
template<int IS_OUT>
__global__ __launch_bounds__(256) void k_mm(const ushort* __restrict__ A,
                                            const ushort* __restrict__ Wt,
                                            const float* __restrict__ bias,
                                            ushort* __restrict__ Qb,
                                            ushort* __restrict__ Kb,
                                            ushort* __restrict__ Vt,
                                            float* __restrict__ Cout) {
    __shared__ __align__(16) char Ab[2][8192];
    __shared__ __align__(16) char Bb[2][8192];
    const int tid = threadIdx.x, lane = tid & 63, wv = tid >> 6;
    const int g = lane >> 4, c16 = lane & 15, l7 = lane & 7;
    const int rsub = lane >> 3, slotx = lane & 7;
    const int m0 = blockIdx.x * 64;
    const int nt = blockIdx.y;

    f32x4 acc[4] = {{0,0,0,0},{0,0,0,0},{0,0,0,0},{0,0,0,0}};

    auto STAGE = [&](int ks, int bufi) {
        const int k0 = ks * 64;
        #pragma unroll
        for (int u = 0; u < 2; ++u) {
            int r0 = wv * 16 + u * 8;
            int row = r0 + rsub;
            int slot = slotx ^ (row & 7);
            GLD16(Ab[bufi] + r0 * 128, A + (size_t)(m0 + row) * QDIM + k0 + slot * 8);
            GLD16(Bb[bufi] + r0 * 128, Wt + (size_t)(nt * 64 + row) * QDIM + k0 + slot * 8);
        }
    };

    const int sl0 = (g ^ l7) * 16, sl1 = ((4 + g) ^ l7) * 16;

    STAGE(0, 0);
    __syncthreads();
    int cur = 0;
    for (int ks = 0; ks < 5; ++ks) {
        if (ks < 4) STAGE(ks + 1, cur ^ 1);
        const char* bbase = Bb[cur] + (wv * 16 + c16) * 128;
        short8 bf0 = *(const short8*)(bbase + sl0);
        short8 bf1 = *(const short8*)(bbase + sl1);
        #pragma unroll
        for (int mi = 0; mi < 4; ++mi) {
            const char* abase = Ab[cur] + (mi * 16 + c16) * 128;
            acc[mi] = __builtin_amdgcn_mfma_f32_16x16x32_bf16(*(const short8*)(abase + sl0), bf0, acc[mi], 0, 0, 0);
            acc[mi] = __builtin_amdgcn_mfma_f32_16x16x32_bf16(*(const short8*)(abase + sl1), bf1, acc[mi], 0, 0, 0);
        }
        __syncthreads();
        cur ^= 1;
    }

    const int ng = nt * 64 + wv * 16 + c16;
    if (IS_OUT) {
        float bv = bias[ng];
        #pragma unroll
        for (int mi = 0; mi < 4; ++mi)
            #pragma unroll
            for (int r = 0; r < 4; ++r) {
                int m = m0 + mi * 16 + g * 4 + r;
                if (m < M_ROWS) Cout[(size_t)m * QDIM + ng] = acc[mi][r] + bv;
            }
    } else {
        int p = ng / QDIM, nn = ng - p * QDIM;
        int h = nn / DHEAD, d = nn - h * DHEAD;
        if (p == 2) {
            #pragma unroll
            for (int mi = 0; mi < 4; ++mi) {
                int m = m0 + mi * 16 + g * 4;        // 4-aligned; N_TOK%4==0
                if (m >= M_ROWS) continue;
                int b = m / N_TOK, tok = m - b * N_TOK;
                short4v w4;
                w4[0] = (short)f2bf(acc[mi][0]);
                w4[1] = (short)f2bf(acc[mi][1]);
                w4[2] = (short)f2bf(acc[mi][2]);
                w4[3] = (short)f2bf(acc[mi][3]);
                *(short4v*)(Vt + ((size_t)(b * HEADS + h) * 48 + d) * NPAD + tok) = w4;
            }
        } else {
            ushort* base = (p == 0) ? Qb : Kb;
            #pragma unroll
            for (int mi = 0; mi < 4; ++mi)
                #pragma unroll
                for (int r = 0; r < 4; ++r) {
                    int m = m0 + mi * 16 + g * 4 + r;
                    if (m >= M_ROWS) continue;
                    int b = m / N_TOK, tok = m - b * N_TOK;
                    base[((size_t)(b * HEADS + h) * NPAD + tok) * 64 + d] = f2bf(acc[mi][r]);
                }
        }
    }
}

// ---- per-(b,h) max norms via atomics: MQK[bh]=max||q~||^2, MQK[16+bh]=max||k||^2
__global__ __launch_bounds__(256) void k_norm(const ushort* __restrict__ Qb,
                                              const ushort* __restrict__ Kb,
                                              unsigned* __restrict__ MQK) {
    __shared__ float rq[256], rk[256];
    const int bh = blockIdx.x >> 3, part = blockIdx.x & 7;
    const int tid = threadIdx.x;
    float mq = 0.f, mk = 0.f;
    for (int tok = part * 256 + tid; tok < N_TOK; tok += 2048) {
        const ushort* qp = Qb + ((size_t)bh * NPAD + tok) * 64;
        const ushort* kp = Kb + ((size_t)bh * NPAD + tok) * 64;
        float sq = 0.f, sk = 0.f;
        #pragma unroll
        for (int d8 = 0; d8 < 40; d8 += 8) {
            short8 a = *(const short8*)(qp + d8);
            short8 c = *(const short8*)(kp + d8);
            #pragma unroll
            for (int j = 0; j < 8; ++j) {
                float fa = bf2f((ushort)a[j]), fc = bf2f((ushort)c[j]);
                sq += fa * fa; sk += fc * fc;
            }
        }
        mq = fmaxf(mq, sq); mk = fmaxf(mk, sk);
    }
    rq[tid] = mq; rk[tid] = mk;
    __syncthreads();
    for (int s = 128; s > 0; s >>= 1) {
        if (tid < s) {
            rq[tid] = fmaxf(rq[tid], rq[tid + s]);
            rk[tid] = fmaxf(rk[tid], rk[tid + s]);
        }
        __syncthreads();
    }
    if (tid == 0) {
        atomicMax(&MQK[bh],      __float_as_uint(rq[0]));
        atomicMax(&MQK[16 + bh], __float_as_uint(rk[0]));
    }
}

// ---- patch pad dims: q[40]=-B_h; Kb d40=1(valid)/0, d41..63=0; Vt row40 = 1 -
__global__ void k_patch(ushort* __restrict__ Qb, ushort* __restrict__ Kb,
                        ushort* __restrict__ Vt, const unsigned* __restrict__ MQK) {
    int gid = blockIdx.x * blockDim.x + threadIdx.x;
    if (gid >= 16 * NPAD) return;
    int bh = gid / NPAD, tok = gid - bh * NPAD;
    float B = sqrtf(__uint_as_float(MQK[bh])) * sqrtf(__uint_as_float(MQK[16 + bh]));
    Qb[(size_t)gid * 64 + 40] = f2bf(-B);
    short8 z = {0, 0, 0, 0, 0, 0, 0, 0};
    short8 k1 = z;
    k1[0] = (short)((tok < N_TOK) ? 0x3F80 : 0);      // k[40]
    ushort* krow = Kb + (size_t)gid * 64;
    *(short8*)(krow + 40) = k1;                        // d 40..47
    *(short8*)(krow + 48) = z;                         // d 48..55
    *(short8*)(krow + 56) = z;                         // d 56..63
    Vt[((size_t)bh * 48 + 40) * NPAD + tok] = (tok < N_TOK) ? (ushort)0x3F80 : (ushort)0;
}

// ------------------------------ mask predicate ------------------------------
__device__ __forceinline__ bool mask_ok(int i, int j, unsigned bi, unsigned bj) {
    if (j >= N_TOK) return false;
    if (i == j) return true;
    if (i < WH) {
        if (j < WH) return (bi & bj) != 0u;
        if (j >= WH + 4 * NOBJ) return true;
        int cI = j - WH;
        if ((unsigned)(cI - NOBJ) < (unsigned)(2 * NOBJ)) return true;
        int om = (cI < NOBJ) ? cI : cI - 3 * NOBJ;
        return ((bi >> om) & 1u) != 0u;
    }
    if (j >= WH) return true;
    if (i >= WH + 4 * NOBJ) return true;
    int rI = i - WH;
    if ((unsigned)(rI - NOBJ) < (unsigned)(2 * NOBJ)) return true;
    int om = (rI < NOBJ) ? rI : rI - 3 * NOBJ;
    return ((bj >> om) & 1u) != 0u;
}

// ------ fused attention: split-K x4; 4 waves x 32q; 64-key tiles;
// ------ two-barrier staging; l via PV MFMA (ones-row); bf16 partials --------
__global__ __launch_bounds__(256, 4) void k_attn(const ushort* __restrict__ Qb,
                                                 const ushort* __restrict__ Kb,
                                                 const ushort* __restrict__ Vt,
                                                 const unsigned* __restrict__ bits,
                                                 ushort* __restrict__ Opart,
                                                 float* __restrict__ Lpart) {
    __shared__ __align__(16) char KtB[64 * 128];     // 8 KB  [key][64 d]
    __shared__ __align__(16) char VtB[48 * 128];     // 6 KB  [d][64 k]
    __shared__ __align__(16) char PsB[4 * 4096];     // 16 KB per-wave P
    __shared__ __align__(16) unsigned bJB[64];

    const int tid = threadIdx.x;
    const int lane = tid & 63, wv = tid >> 6;
    const int g = lane >> 4, c16 = lane & 15;
    const int l7x = c16 & 7;
    const int rsub = lane >> 3, slotx = lane & 7;

    // XCD-chunked bijective swizzle: 2176 = 8 * 272.
    const int bid = blockIdx.x;
    const int logical = (bid & 7) * 272 + (bid >> 3);
    const int grp = logical / NQT;                 // 0..63 = (bh, ks)
    const int qt = logical - grp * NQT;
    const int bh = grp >> 2, ks = grp & 3;
    const int b = bh >> 3;
    const int q0w = qt * 128 + wv * 32;
    const int iqA = q0w + c16, iqB = iqA + 16;
    const bool vis_i = (qt < 32);
    const int t0 = ks * NTH;                       // first global 64-key tile

    short8 qA0, qA1, qB0, qB1;
    {
        const ushort* qp = Qb + ((size_t)bh * NPAD + iqA) * 64 + g * 8;
        qA0 = *(const short8*)(qp);
        qA1 = *(const short8*)(qp + 32);
        qB0 = *(const short8*)(qp + 16 * 64);
        qB1 = *(const short8*)(qp + 16 * 64 + 32);
    }
    const unsigned bI_A = bits[(size_t)b * NPAD + iqA];
    const unsigned bI_B = bits[(size_t)b * NPAD + iqB];

    // staging pointers (strength-reduced), starting at this quarter's key base
    const ushort* kp = Kb + ((size_t)bh * NPAD + t0 * 64 + wv * 16 + rsub) * 64 + (slotx ^ rsub) * 8;
    const ushort* vbase = Vt + (size_t)bh * 48 * NPAD;
    int voff0 = 0, voff1 = 0;
    if (wv < 3) {
        int d0 = wv * 16 + rsub, d1 = d0 + 8;
        voff0 = d0 * NPAD + (slotx ^ rsub) * 8;
        voff1 = d1 * NPAD + (slotx ^ rsub) * 8;
    }
    const unsigned* bp = bits + (size_t)b * NPAD + t0 * 64 + lane;

    auto STAGE_K = [&](const ushort* kpt) {
        GLD16(KtB + (wv * 16) * 128, kpt);
        GLD16(KtB + (wv * 16 + 8) * 128, kpt + 512);
    };
    auto STAGE_V = [&](int j0) {
        if (wv < 3) {
            GLD16(VtB + (wv * 16) * 128, vbase + j0 + voff0);
            GLD16(VtB + (wv * 16 + 8) * 128, vbase + j0 + voff1);
        }
    };
    auto STAGE_B = [&](const unsigned* bpt) {
        if (wv == 3) GLD4(bJB, bpt);
    };

    const int sl0 = (g ^ l7x) * 16;
    const int sl1 = ((4 + g) ^ l7x) * 16;
    const int pswA = wv * 4096 + c16 * 128;          // sub A row
    const int pswB = pswA + 2048;                    // sub B row
    const int swz = l7x << 4;

    f32x4 oA0 = {0,0,0,0}, oA1 = oA0, oA2 = oA0;
    f32x4 oB0 = oA0, oB1 = oA0, oB2 = oA0;

    STAGE_K(kp); STAGE_V(t0 * 64); STAGE_B(bp);
    __syncthreads();

    for (int t = 0; t < NTH; ++t) {
        const int tg = t0 + t;
        const int j0 = tg * 64;

        // ---- S + softmax + P-write, fused per kt (both q-subs) ----
        auto do_tile = [&](auto okA_fn, auto okB_fn) {
            #pragma unroll
            for (int kt = 0; kt < 4; ++kt) {
                const char* arow = KtB + (kt * 16 + c16) * 128;
                short8 a0 = *(const short8*)(arow + sl0);
                short8 a1 = *(const short8*)(arow + sl1);
                f32x4 sA = {0,0,0,0}, sB = {0,0,0,0};
                __builtin_amdgcn_s_setprio(1);
                sA = __builtin_amdgcn_mfma_f32_16x16x32_bf16(a0, qA0, sA, 0, 0, 0);
                sA = __builtin_amdgcn_mfma_f32_16x16x32_bf16(a1, qA1, sA, 0, 0, 0);
                sB = __builtin_amdgcn_mfma_f32_16x16x32_bf16(a0, qB0, sB, 0, 0, 0);
                sB = __builtin_amdgcn_mfma_f32_16x16x32_bf16(a1, qB1, sB, 0, 0, 0);
                __builtin_amdgcn_s_setprio(0);
                uintx4 bk = *(const uintx4*)&bJB[kt * 16 + g * 4];
                float pA[4], pB[4];
                #pragma unroll
                for (int r = 0; r < 4; ++r) {
                    int j = j0 + kt * 16 + g * 4 + r;
                    float eA = __builtin_amdgcn_exp2f(sA[r]);
                    float eB = __builtin_amdgcn_exp2f(sB[r]);
                    pA[r] = okA_fn(j, bk[r]) ? eA : 0.f;
                    pB[r] = okB_fn(j, bk[r]) ? eB : 0.f;
                }
                unsigned wA0, wA1, wB0, wB1;
                asm("v_cvt_pk_bf16_f32 %0, %1, %2" : "=v"(wA0) : "v"(pA[0]), "v"(pA[1]));
                asm("v_cvt_pk_bf16_f32 %0, %1, %2" : "=v"(wA1) : "v"(pA[2]), "v"(pA[3]));
                asm("v_cvt_pk_bf16_f32 %0, %1, %2" : "=v"(wB0) : "v"(pB[0]), "v"(pB[1]));
                asm("v_cvt_pk_bf16_f32 %0, %1, %2" : "=v"(wB1) : "v"(pB[2]), "v"(pB[3]));
                uint2 vA; vA.x = wA0; vA.y = wA1;
                uint2 vB; vB.x = wB0; vB.y = wB1;
                int po = (kt * 32 + g * 8) ^ swz;
                *(uint2*)(PsB + pswA + po) = vA;
                *(uint2*)(PsB + pswB + po) = vB;
            }
        };

        const bool vis_j = (j0 + 64 <= WH);
        if (vis_i && vis_j && ((tg >> 1) != qt)) {
            do_tile([&](int j, unsigned bj) { return (bI_A & bj) != 0u; },
                    [&](int j, unsigned bj) { return (bI_B & bj) != 0u; });
        } else if (vis_i && vis_j) {
            do_tile([&](int j, unsigned bj) { return ((bI_A & bj) != 0u) || (iqA == j); },
                    [&](int j, unsigned bj) { return ((bI_B & bj) != 0u) || (iqB == j); });
        } else {
            do_tile([&](int j, unsigned bj) { return mask_ok(iqA, j, bI_A, bj); },
                    [&](int j, unsigned bj) { return mask_ok(iqB, j, bI_B, bj); });
        }

        __syncthreads();                       // A: all done reading K_t
        kp += 64 * 64; bp += 64;
        if (t + 1 < NTH) { STAGE_K(kp); STAGE_B(bp); }

        // ---- PV: 12 MFMA; d=40 col of oA2/oB2 accumulates l (ones-row) ----
        short8 paA0 = *(const short8*)(PsB + pswA + sl0);
        short8 paA1 = *(const short8*)(PsB + pswA + sl1);
        short8 paB0 = *(const short8*)(PsB + pswB + sl0);
        short8 paB1 = *(const short8*)(PsB + pswB + sl1);
        {
            const char* v0r = VtB + (0 * 16 + c16) * 128;
            const char* v1r = VtB + (1 * 16 + c16) * 128;
            const char* v2r = VtB + (2 * 16 + c16) * 128;
            short8 v00 = *(const short8*)(v0r + sl0), v01 = *(const short8*)(v0r + sl1);
            short8 v10 = *(const short8*)(v1r + sl0), v11 = *(const short8*)(v1r + sl1);
            short8 v20 = *(const short8*)(v2r + sl0), v21 = *(const short8*)(v2r + sl1);
            __builtin_amdgcn_s_setprio(1);
            oA0 = __builtin_amdgcn_mfma_f32_16x16x32_bf16(paA0, v00, oA0, 0, 0, 0);
            oA0 = __builtin_amdgcn_mfma_f32_16x16x32_bf16(paA1, v01, oA0, 0, 0, 0);
            oB0 = __builtin_amdgcn_mfma_f32_16x16x32_bf16(paB0, v00, oB0, 0, 0, 0);
            oB0 = __builtin_amdgcn_mfma_f32_16x16x32_bf16(paB1, v01, oB0, 0, 0, 0);
            oA1 = __builtin_amdgcn_mfma_f32_16x16x32_bf16(paA0, v10, oA1, 0, 0, 0);
            oA1 = __builtin_amdgcn_mfma_f32_16x16x32_bf16(paA1, v11, oA1, 0, 0, 0);
            oB1 = __builtin_amdgcn_mfma_f32_16x16x32_bf16(paB0, v10, oB1, 0, 0, 0);
            oB1 = __builtin_amdgcn_mfma_f32_16x16x32_bf16(paB1, v11, oB1, 0, 0, 0);
            oA2 = __builtin_amdgcn_mfma_f32_16x16x32_bf16(paA0, v20, oA2, 0, 0, 0);
            oA2 = __builtin_amdgcn_mfma_f32_16x16x32_bf16(paA1, v21, oA2, 0, 0, 0);
            oB2 = __builtin_amdgcn_mfma_f32_16x16x32_bf16(paB0, v20, oB2, 0, 0, 0);
            oB2 = __builtin_amdgcn_mfma_f32_16x16x32_bf16(paB1, v21, oB2, 0, 0, 0);
            __builtin_amdgcn_s_setprio(0);
        }

        __syncthreads();                       // B: all done reading V_t
        if (t + 1 < NTH) STAGE_V((tg + 1) * 64);
    }

    // ---- store partials: O (bf16) + l (f32, d=40 column, lane c16==8) ----
    const size_t prow = ((size_t)ks * 16 + bh) * NPAD;
    if (c16 == 8) {
        #pragma unroll
        for (int r = 0; r < 4; ++r) {
            Lpart[prow + q0w + g * 4 + r]      = oA2[r];
            Lpart[prow + q0w + 16 + g * 4 + r] = oB2[r];
        }
    }
    #pragma unroll
    for (int r = 0; r < 4; ++r) {
        int qrA = q0w + g * 4 + r;
        int qrB = qrA + 16;
        if (qrA < N_TOK) {
            ushort* dst = Opart + (prow + qrA) * 40;
            dst[c16]      = f2bf(oA0[r]);
            dst[16 + c16] = f2bf(oA1[r]);
            if (c16 < 8) dst[32 + c16] = f2bf(oA2[r]);
        }
        if (qrB < N_TOK) {
            ushort* dst = Opart + (prow + qrB) * 40;
            dst[c16]      = f2bf(oB0[r]);
            dst[16 + c16] = f2bf(oB1[r]);
            if (c16 < 8) dst[32 + c16] = f2bf(oB2[r]);
        }
    }
}

// ---------- combine: O = sum(Ok)/sum(lk), write bf16 AOb --------------------
__global__ __launch_bounds__(256) void k_comb(const ushort* __restrict__ Opart,
                                              const float* __restrict__ Lpart,
                                              ushort* __restrict__ AOb) {
    int gid = blockIdx.x * blockDim.x + threadIdx.x;
    if (gid >= 16 * N_TOK * 10) return;
    int row = gid / 10, v = gid - row * 10;
    int bh = row / N_TOK, q = row - bh * N_TOK;
    f32x4 s = {0.f, 0.f, 0.f, 0.f};
    float l = 0.f;
    #pragma unroll
    for (int ks = 0; ks < KSPLIT; ++ks) {
        size_t rr = ((size_t)ks * 16 + bh) * NPAD + q;
        short4v a = *(const short4v*)(Opart + rr * 40 + v * 4);
        s[0] += bf2f((ushort)a[0]); s[1] += bf2f((ushort)a[1]);
        s[2] += bf2f((ushort)a[2]); s[3] += bf2f((ushort)a[3]);
        l += Lpart[rr];
    }
    float inv = 1.f / l;
    int b = bh >> 3, h = bh & 7;
    short4v o;
    o[0] = (short)f2bf(s[0] * inv);
    o[1] = (short)f2bf(s[1] * inv);
    o[2] = (short)f2bf(s[2] * inv);
    o[3] = (short)f2bf(s[3] * inv);
    *(short4v*)(AOb + (size_t)(b * N_TOK + q) * QDIM + h * DHEAD + v * 4) = o;
}

// --------------------------------- launcher ---------------------------------
extern "C" void kernel_launch(void* const* d_in, const int* in_sizes, int n_in,
                              void* d_out, int out_size, void* d_ws, size_t ws_size,
                              hipStream_t stream) {
    const float* x   = (const float*)d_in[0];
    const float* att = (const float*)d_in[1];
    const float* Wq  = (const float*)d_in[2];
    const float* Wk  = (const float*)d_in[3];
    const float* Wv  = (const float*)d_in[4];
    const float* Wo  = (const float*)d_in[5];
    const float* bo  = (const float*)d_in[6];
    float* out = (float*)d_out;

    char* w = (char*)d_ws;
    unsigned* bits = (unsigned*)w;                      // BB*NPAD*4 = 34.8 KB
    unsigned* MQK = (unsigned*)(w + 40960);             // 32 uints
    size_t off = 65536;
    ushort* xb    = (ushort*)(w + off); off += (size_t)MPAD * QDIM * 2;
    ushort* WtAll = (ushort*)(w + off); off += (size_t)1280 * QDIM * 2;
    ushort* Qb    = (ushort*)(w + off); off += (size_t)16 * NPAD * 64 * 2;
    ushort* Kb    = (ushort*)(w + off); off += (size_t)16 * NPAD * 64 * 2;
    ushort* Vt    = (ushort*)(w + off); off += (size_t)16 * 48 * NPAD * 2;
    ushort* AOb   = (ushort*)(w + off); off += (size_t)MPAD * QDIM * 2;
    ushort* Opart = (ushort*)(w + off); off += (size_t)KSPLIT * 16 * NPAD * 40 * 2;
    float*  Lpart = (float*)(w + off);

    k_pre<<<(M_ROWS * QDIM / 8 + 255) / 256, 256, 0, stream>>>(x, xb, att, bits, MQK);
    k_wcvt<<<dim3(10, 40), 256, 0, stream>>>(Wq, Wk, Wv, Wo, WtAll);

    k_mm<0><<<dim3(MPAD / 64, 15), 256, 0, stream>>>(xb, WtAll, nullptr, Qb, Kb, Vt, nullptr);
    k_norm<<<128, 256, 0, stream>>>(Qb, Kb, MQK);
    k_patch<<<(16 * NPAD + 255) / 256, 256, 0, stream>>>(Qb, Kb, Vt, MQK);
    k_attn<<<16 * NQT * KSPLIT, 256, 0, stream>>>(Qb, Kb, Vt, bits, Opart, Lpart);
    k_comb<<<(16 * N_TOK * 10 + 255) / 256, 256, 0, stream>>>(Opart, Lpart, AOb);
    k_mm<1><<<dim3(MPAD / 64, 5), 256, 0, stream>>>(AOb, WtAll + 960 * QDIM, bo,
                                                    nullptr, nullptr, nullptr, out);
}